// Round 2
// baseline (183.285 us; speedup 1.0000x reference)
//
#include <hip/hip_runtime.h>

// Problem constants (SubOut_60206851555968): B=8, U=E=1024, D=P=256, fp32 in/out.
#define BDIM 8
#define UDIM 1024
#define EDIM 1024
#define DDIM 256
#define PDIM 256

typedef __attribute__((ext_vector_type(8))) short bf16x8;   // 8 bf16 = 4 VGPRs
typedef __attribute__((ext_vector_type(4))) float f32x4;

__device__ __forceinline__ short f2bf(float x) {
    unsigned u = __float_as_uint(x);
    unsigned r = (u + 0x7FFFu + ((u >> 16) & 1u)) >> 16;   // RNE
    return (short)r;
}

// Async global->LDS DMA, 16B per lane. LDS dest is wave-uniform base + lane*16;
// global src is per-lane. Counts on vmcnt. The compiler cannot sink/serialize
// this (side-effecting intrinsic, no result VGPRs) — structural MLP.
__device__ __forceinline__ void dma16(const void* g, void* lds) {
    __builtin_amdgcn_global_load_lds(
        (const __attribute__((address_space(1))) unsigned*)g,
        (__attribute__((address_space(3))) unsigned*)lds, 16, 0, 0);
}

// ---------------------------------------------------------------------------
// prep: wT[n][k] = bf16(w[k][n]); zero sums + out.  (unchanged from v2)
// ---------------------------------------------------------------------------
__global__ __launch_bounds__(256) void prep_kernel(
    const float* __restrict__ w, ushort* __restrict__ wT,
    float* __restrict__ sums /* row_sums||col_sums, 16384 */,
    float* __restrict__ out, int out_size)
{
    int k  = threadIdx.x;          // D index
    int n0 = blockIdx.x * 4;       // P index base
    float4 wv = *(const float4*)(w + (size_t)k * PDIM + n0);
    wT[(size_t)(n0 + 0) * DDIM + k] = (ushort)f2bf(wv.x);
    wT[(size_t)(n0 + 1) * DDIM + k] = (ushort)f2bf(wv.y);
    wT[(size_t)(n0 + 2) * DDIM + k] = (ushort)f2bf(wv.z);
    wT[(size_t)(n0 + 3) * DDIM + k] = (ushort)f2bf(wv.w);
    int g = blockIdx.x * 256 + k;
    sums[g] = 0.f;                              // exactly 16384
    if (g < out_size) out[g] = 0.f;
}

// ---------------------------------------------------------------------------
// proj: u_p/e_p = bf16(enc @ w + bias), MFMA 16x16x32 bf16. (unchanged v2)
// ---------------------------------------------------------------------------
__global__ __launch_bounds__(256) void proj_kernel(
    const float* __restrict__ u_enc, const float* __restrict__ e_enc,
    const ushort* __restrict__ wT, const float* __restrict__ bias,
    ushort* __restrict__ u_p, ushort* __restrict__ e_p)
{
    int bid  = blockIdx.x;                 // 0..1023
    int lin  = (bid & 7) * 128 + (bid >> 3);
    int row0 = (lin >> 2) * 64;
    int col0 = (lin & 3) * 64;

    const float* A; ushort* C;
    if (row0 < BDIM * UDIM) { A = u_enc; C = u_p; }
    else                    { A = e_enc; C = e_p; row0 -= BDIM * UDIM; }

    int tid  = threadIdx.x;
    int wave = tid >> 6, lane = tid & 63;
    int m = lane & 15, quad = lane >> 4;

    const float* aptr = A + (size_t)(row0 + wave * 16 + m) * DDIM + quad * 8;

    float4 a[16];
    #pragma unroll
    for (int i = 0; i < 8; ++i) {
        a[2 * i]     = *(const float4*)(aptr + 32 * i);
        a[2 * i + 1] = *(const float4*)(aptr + 32 * i + 4);
    }

    f32x4 acc[4] = {};
    #pragma unroll
    for (int i = 0; i < 8; ++i) {
        bf16x8 af;
        af[0] = f2bf(a[2*i].x);   af[1] = f2bf(a[2*i].y);
        af[2] = f2bf(a[2*i].z);   af[3] = f2bf(a[2*i].w);
        af[4] = f2bf(a[2*i+1].x); af[5] = f2bf(a[2*i+1].y);
        af[6] = f2bf(a[2*i+1].z); af[7] = f2bf(a[2*i+1].w);
        int k0 = 32 * i;
        #pragma unroll
        for (int nt = 0; nt < 4; ++nt) {
            bf16x8 bfr = *(const bf16x8*)(wT + (size_t)(col0 + nt * 16 + m) * DDIM + k0 + quad * 8);
            acc[nt] = __builtin_amdgcn_mfma_f32_16x16x32_bf16(af, bfr, acc[nt], 0, 0, 0);
        }
    }

    #pragma unroll
    for (int nt = 0; nt < 4; ++nt) {
        int col = col0 + nt * 16 + m;
        float bv = bias[col];
        #pragma unroll
        for (int r = 0; r < 4; ++r) {
            int row = row0 + wave * 16 + quad * 4 + r;
            C[(size_t)row * PDIM + col] = (ushort)f2bf(acc[nt][r] + bv);
        }
    }
}

// ---------------------------------------------------------------------------
// fused v4: op = u_p . e_p (MFMA), gate, row/col reduction.
// Latency attack, take 2. v3's register-batched epilogue loads were provably
// deleted by the compiler (VGPR=40 < the >=80 the batch requires; dur
// unchanged). This version uses global_load_lds: each wave ASYNC-stages its
// own 16 rows of the 64x64 pair/mask tiles into LDS at wave start (8 DMA
// instrs, zero VGPRs, deep vmcnt queue). The ~500-900cy HBM/L3 latency then
// overlaps the whole MFMA loop; the epilogue reads LDS. No barrier needed:
// every wave reads only rows it staged itself (own vmcnt(0) suffices).
// LDS 33KB -> 4 blocks/CU.
// ---------------------------------------------------------------------------
__global__ __launch_bounds__(256) void fused_kernel(
    const ushort* __restrict__ u_p, const ushort* __restrict__ e_p,
    const float* __restrict__ pair_enc, const float* __restrict__ ue_mask,
    const float* __restrict__ bpp_w_p, const float* __restrict__ bpp_b_p,
    float* __restrict__ row_sums, float* __restrict__ col_sums)
{
    __shared__ float lds_pair[64][64];   // 16 KB
    __shared__ float lds_mask[64][64];   // 16 KB
    __shared__ float colred[4][64];      // 1 KB

    int bid  = blockIdx.x;          // 0..2047
    int b    = bid & 7;             // batch <-> XCD (kept: FETCH 51->37MB)
    int tile = bid >> 3;            // 0..255
    int iu = tile >> 4, ie = tile & 15;
    int u0 = iu * 64, e0 = ie * 64;

    int tid  = threadIdx.x;
    int wave = tid >> 6, lane = tid & 63;
    int m = lane & 15, quad = lane >> 4;

    const float* pm = pair_enc + (size_t)b * UDIM * EDIM;
    const float* mm = ue_mask  + (size_t)b * UDIM * EDIM;

    // ---- async stage: wave w owns tile rows [16w, 16w+16) ----
    // One dma16 covers 4 rows x 64 floats (lane l -> row +(l>>4), col (l&15)*4).
    {
        int lr = lane >> 4;
        int lc = (lane & 15) * 4;
        #pragma unroll
        for (int j = 0; j < 4; ++j) {
            int r0 = wave * 16 + j * 4;
            size_t goff = (size_t)(u0 + r0 + lr) * EDIM + e0 + lc;
            dma16(pm + goff, &lds_pair[r0][0]);
            dma16(mm + goff, &lds_mask[r0][0]);
        }
    }

    const ushort* Au = u_p + (size_t)b * UDIM * PDIM + (size_t)(u0 + wave * 16 + m) * PDIM + quad * 8;
    const ushort* Be = e_p + (size_t)b * EDIM * PDIM + (size_t)(e0 + m) * PDIM + quad * 8;

    bf16x8 af[8];
    #pragma unroll
    for (int i = 0; i < 8; ++i) af[i] = *(const bf16x8*)(Au + 32 * i);

    float bw = bpp_w_p[0], bb = bpp_b_p[0];

    f32x4 acc[4] = {};
    #pragma unroll
    for (int i = 0; i < 8; ++i) {
        #pragma unroll
        for (int nt = 0; nt < 4; ++nt) {
            bf16x8 bfr = *(const bf16x8*)(Be + (size_t)nt * 16 * PDIM + 32 * i);
            acc[nt] = __builtin_amdgcn_mfma_f32_16x16x32_bf16(af[i], bfr, acc[nt], 0, 0, 0);
        }
    }

    // Drain our DMAs (they were issued before everything above — long done by
    // now in steady state). "memory" keeps the LDS reads below this point.
    asm volatile("s_waitcnt vmcnt(0)" ::: "memory");

    // Epilogue: gate + partial sums from LDS. C layout: row = quad*4+reg,
    // col = lane&15 (+16*nt).
    float rsum[4] = {0.f, 0.f, 0.f, 0.f};
    float csum[4] = {0.f, 0.f, 0.f, 0.f};
    #pragma unroll
    for (int r = 0; r < 4; ++r) {
        int row = wave * 16 + quad * 4 + r;   // tile-local; staged by this wave
        #pragma unroll
        for (int nt = 0; nt < 4; ++nt) {
            int col = nt * 16 + m;
            float mv = lds_mask[row][col];
            float pv = lds_pair[row][col];
            float arg = bw * pv + bb + mv * acc[nt][r];
            float s = mv / (1.f + __expf(-arg));
            rsum[r]  += s;
            csum[nt] += s;
        }
    }

    // Row sums: reduce across the 16 lanes of each quad (cols). Row is unique
    // to (wave, quad, r) -> direct atomicAdd from the quad leader.
    #pragma unroll
    for (int r = 0; r < 4; ++r) {
        float v = rsum[r];
        v += __shfl_xor(v, 1); v += __shfl_xor(v, 2);
        v += __shfl_xor(v, 4); v += __shfl_xor(v, 8);
        if (m == 0)
            atomicAdd(&row_sums[(size_t)b * UDIM + u0 + wave * 16 + quad * 4 + r], v);
    }

    // Col sums: reduce across quads (rows within strip), then across waves via LDS.
    #pragma unroll
    for (int nt = 0; nt < 4; ++nt) {
        float v = csum[nt];
        v += __shfl_xor(v, 16); v += __shfl_xor(v, 32);
        if (quad == 0) colred[wave][nt * 16 + m] = v;
    }
    __syncthreads();

    if (tid < 64) {
        float v = colred[0][tid] + colred[1][tid] + colred[2][tid] + colred[3][tid];
        atomicAdd(&col_sums[(size_t)b * EDIM + e0 + tid], v);
    }
}

// ---------------------------------------------------------------------------
// finish: out[b,0:256] = row_sums[b,:] @ u_enc[b]; out[b,256:512] = col_sums @ e_enc.
// (unchanged v2)
// ---------------------------------------------------------------------------
__global__ __launch_bounds__(256) void finish_kernel(
    const float* __restrict__ u_enc, const float* __restrict__ e_enc,
    const float* __restrict__ row_sums, const float* __restrict__ col_sums,
    float* __restrict__ out)
{
    int b = blockIdx.x;
    int half = blockIdx.y;
    int chunk = blockIdx.z;        // 0..63
    int d = threadIdx.x;

    const float* enc = half ? e_enc : u_enc;
    const float* s   = half ? col_sums : row_sums;

    int base = chunk * 16;
    float ev[16];
    #pragma unroll
    for (int j = 0; j < 16; ++j)
        ev[j] = enc[(size_t)(b * UDIM + base + j) * DDIM + d];

    float acc = 0.f;
    #pragma unroll
    for (int j = 0; j < 16; ++j)
        acc += s[(size_t)b * UDIM + base + j] * ev[j];

    atomicAdd(&out[(size_t)b * 2 * DDIM + half * DDIM + d], acc);
}

// ---------------------------------------------------------------------------
extern "C" void kernel_launch(void* const* d_in, const int* in_sizes, int n_in,
                              void* d_out, int out_size, void* d_ws, size_t ws_size,
                              hipStream_t stream)
{
    const float* u_enc    = (const float*)d_in[0];
    const float* e_enc    = (const float*)d_in[1];
    const float* pair_enc = (const float*)d_in[2];
    const float* ue_mask  = (const float*)d_in[3];
    const float* w_kernel = (const float*)d_in[4];
    const float* w_bias   = (const float*)d_in[5];
    const float* bpp_w    = (const float*)d_in[6];
    const float* bpp_b    = (const float*)d_in[7];
    float* out = (float*)d_out;

    // ws layout: u_p bf16 (4MB) | e_p bf16 (4MB) | wT bf16 (128KB) | sums fp32 (64KB)
    ushort* u_p = (ushort*)d_ws;
    ushort* e_p = u_p + (size_t)BDIM * UDIM * PDIM;
    ushort* wT  = e_p + (size_t)BDIM * EDIM * PDIM;
    float* row_sums = (float*)(wT + (size_t)DDIM * PDIM);
    float* col_sums = row_sums + BDIM * UDIM;

    prep_kernel<<<dim3(64), 256, 0, stream>>>(w_kernel, wT, row_sums, out, out_size);

    proj_kernel<<<dim3(1024), 256, 0, stream>>>(u_enc, e_enc, wT, w_bias, u_p, e_p);

    fused_kernel<<<dim3(2048), 256, 0, stream>>>(u_p, e_p, pair_enc, ue_mask,
                                                 bpp_w, bpp_b, row_sums, col_sums);

    finish_kernel<<<dim3(BDIM, 2, 64), 256, 0, stream>>>(u_enc, e_enc, row_sums, col_sums, out);
}

// Round 3
// 155.808 us; speedup vs baseline: 1.1764x; 1.1764x over previous
//
#include <hip/hip_runtime.h>

// Problem constants (SubOut_60206851555968): B=8, U=E=1024, D=P=256, fp32 in/out.
#define BDIM 8
#define UDIM 1024
#define EDIM 1024
#define DDIM 256
#define PDIM 256

typedef __attribute__((ext_vector_type(8))) short bf16x8;   // 8 bf16 = 4 VGPRs
typedef __attribute__((ext_vector_type(4))) float f32x4;

__device__ __forceinline__ short f2bf(float x) {
    unsigned u = __float_as_uint(x);
    unsigned r = (u + 0x7FFFu + ((u >> 16) & 1u)) >> 16;   // RNE
    return (short)r;
}

// Async global->LDS DMA, 16B per lane. LDS dest = wave-uniform base + lane*16;
// global src is per-lane (this is how swizzled LDS layouts are built: pre-swizzle
// the SOURCE, keep the dest linear — both-sides-or-neither rule).
__device__ __forceinline__ void dma16(const void* g, void* lds) {
    __builtin_amdgcn_global_load_lds(
        (const __attribute__((address_space(1))) unsigned*)g,
        (__attribute__((address_space(3))) unsigned*)lds, 16, 0, 0);
}

// ---------------------------------------------------------------------------
// prep: wT[n][k] = bf16(w[k][n]); zero sums + out.  (unchanged)
// ---------------------------------------------------------------------------
__global__ __launch_bounds__(256) void prep_kernel(
    const float* __restrict__ w, ushort* __restrict__ wT,
    float* __restrict__ sums /* row_sums||col_sums, 16384 */,
    float* __restrict__ out, int out_size)
{
    int k  = threadIdx.x;          // D index
    int n0 = blockIdx.x * 4;       // P index base
    float4 wv = *(const float4*)(w + (size_t)k * PDIM + n0);
    wT[(size_t)(n0 + 0) * DDIM + k] = (ushort)f2bf(wv.x);
    wT[(size_t)(n0 + 1) * DDIM + k] = (ushort)f2bf(wv.y);
    wT[(size_t)(n0 + 2) * DDIM + k] = (ushort)f2bf(wv.z);
    wT[(size_t)(n0 + 3) * DDIM + k] = (ushort)f2bf(wv.w);
    int g = blockIdx.x * 256 + k;
    sums[g] = 0.f;                              // exactly 16384
    if (g < out_size) out[g] = 0.f;
}

// ---------------------------------------------------------------------------
// proj v3: u_p/e_p = bf16(enc @ w + bias), MFMA 16x16x32 bf16.
// wT B-tile (64 cols x 256 k = 32KB bf16) now staged ONCE per block into LDS
// via global_load_lds with XOR-swizzle (linear [64][256] bf16 would be a
// 16-way bank conflict on ds_read_b128). Previously each of the 4 waves
// re-read the whole tile from L2/L3 with MLP~1 — the latency chain that
// dominated. One vmcnt(0)+barrier drain per block; MFMA loop runs from LDS.
// ---------------------------------------------------------------------------
__global__ __launch_bounds__(256) void proj_kernel(
    const float* __restrict__ u_enc, const float* __restrict__ e_enc,
    const ushort* __restrict__ wT, const float* __restrict__ bias,
    ushort* __restrict__ u_p, ushort* __restrict__ e_p)
{
    __shared__ ushort lds_b[64 * 256];   // 32 KB, swizzled: elem(rl,cb): byte = rl*512 + (cb ^ ((rl&7)<<4))

    int bid  = blockIdx.x;                 // 0..1023
    int lin  = (bid & 7) * 128 + (bid >> 3);
    int row0 = (lin >> 2) * 64;
    int col0 = (lin & 3) * 64;

    const float* A; ushort* C;
    if (row0 < BDIM * UDIM) { A = u_enc; C = u_p; }
    else                    { A = e_enc; C = e_p; row0 -= BDIM * UDIM; }

    int tid  = threadIdx.x;
    int wave = tid >> 6, lane = tid & 63;
    int m = lane & 15, quad = lane >> 4;

    // ---- stage wT rows [col0, col0+64) into LDS, swizzled source ----
    // dma j covers 2 rows; lane l -> local row rl = wave*16 + 2j + (l>>5),
    // byte-in-row cb = (l&31)*16; src col-bytes = cb ^ ((rl&7)<<4).
    {
        int rl_base = wave * 16;
        int lr = lane >> 5;            // 0/1
        int cb = (lane & 31) * 16;     // 0..496
        #pragma unroll
        for (int j = 0; j < 8; ++j) {
            int rl = rl_base + 2 * j + lr;
            const ushort* src = wT + (size_t)(col0 + rl) * DDIM + ((cb ^ ((rl & 7) << 4)) >> 1);
            dma16(src, &lds_b[(size_t)(rl_base + 2 * j) * DDIM]);
        }
    }

    // ---- A strip: 16 float4 batched into registers (one latency, shares the
    // vmcnt drain below) ----
    const float* aptr = A + (size_t)(row0 + wave * 16 + m) * DDIM + quad * 8;
    float4 a[16];
    #pragma unroll
    for (int i = 0; i < 8; ++i) {
        a[2 * i]     = *(const float4*)(aptr + 32 * i);
        a[2 * i + 1] = *(const float4*)(aptr + 32 * i + 4);
    }

    asm volatile("s_waitcnt vmcnt(0)" ::: "memory");
    __syncthreads();

    int rowmask = (m & 7) << 4;        // swizzle term: row = nt*16 + m -> row&7 = m&7
    f32x4 acc[4] = {};
    #pragma unroll
    for (int i = 0; i < 8; ++i) {
        bf16x8 af;
        af[0] = f2bf(a[2*i].x);   af[1] = f2bf(a[2*i].y);
        af[2] = f2bf(a[2*i].z);   af[3] = f2bf(a[2*i].w);
        af[4] = f2bf(a[2*i+1].x); af[5] = f2bf(a[2*i+1].y);
        af[6] = f2bf(a[2*i+1].z); af[7] = f2bf(a[2*i+1].w);
        #pragma unroll
        for (int nt = 0; nt < 4; ++nt) {
            int elem = (nt * 16 + m) * DDIM + (((quad * 16 + 64 * i) ^ rowmask) >> 1);
            bf16x8 bfr = *(const bf16x8*)(lds_b + elem);
            acc[nt] = __builtin_amdgcn_mfma_f32_16x16x32_bf16(af, bfr, acc[nt], 0, 0, 0);
        }
    }

    // C/D layout: col = lane&15, row = quad*4 + reg.
    #pragma unroll
    for (int nt = 0; nt < 4; ++nt) {
        int col = col0 + nt * 16 + m;
        float bv = bias[col];
        #pragma unroll
        for (int r = 0; r < 4; ++r) {
            int row = row0 + wave * 16 + quad * 4 + r;
            C[(size_t)row * PDIM + col] = (ushort)f2bf(acc[nt][r] + bv);
        }
    }
}

// ---------------------------------------------------------------------------
// fused v5: op = u_p . e_p (MFMA), gate, row/col reduction.
// Diagnosis from v2-v4 counters: ~29k stall cycles/wave = ~40 frag loads x
// ~700cy L3 latency, MLP~1. pair/mask streaming (16MB/XCD/gen) evicts
// u_p/e_p from the 4MB L2, so every wave's re-read of the 32KB e-tile
// chained through Infinity Cache. Fix = m97 structure:
//   * e-tile staged ONCE per block into swizzled LDS (4 waves share it).
//   * pair/mask tiles staged into LDS by the same DMA queue.
//   * af frag loads issued into the same FIFO.
//   * ONE vmcnt(0)+barrier drain; MFMA loop + epilogue run from LDS/regs.
// LDS 65.25KB -> 2 blocks/CU; incoming block's stage overlaps resident
// block's compute. v4's FIFO-poisoning (per-use waits behind DMAs) is gone
// because there are no post-barrier global loads at all.
// ---------------------------------------------------------------------------
__global__ __launch_bounds__(256) void fused_kernel(
    const ushort* __restrict__ u_p, const ushort* __restrict__ e_p,
    const float* __restrict__ pair_enc, const float* __restrict__ ue_mask,
    const float* __restrict__ bpp_w_p, const float* __restrict__ bpp_b_p,
    float* __restrict__ row_sums, float* __restrict__ col_sums)
{
    __shared__ ushort lds_e[64 * 256];   // 32 KB, swizzled (same scheme as proj)
    __shared__ float lds_pair[64][64];   // 16 KB, linear
    __shared__ float lds_mask[64][64];   // 16 KB, linear
    __shared__ float colred[4][64];      // 1 KB

    int bid  = blockIdx.x;          // 0..2047
    int b    = bid & 7;             // batch <-> XCD (kept: FETCH 51->37MB)
    int tile = bid >> 3;            // 0..255
    int iu = tile >> 4, ie = tile & 15;
    int u0 = iu * 64, e0 = ie * 64;

    int tid  = threadIdx.x;
    int wave = tid >> 6, lane = tid & 63;
    int m = lane & 15, quad = lane >> 4;

    const float* pm = pair_enc + (size_t)b * UDIM * EDIM;
    const float* mm = ue_mask  + (size_t)b * UDIM * EDIM;
    const ushort* eb = e_p + (size_t)b * EDIM * PDIM;

    // ---- stage e-tile rows [e0, e0+64) into swizzled LDS ----
    {
        int rl_base = wave * 16;
        int lr = lane >> 5;            // 0/1
        int cb = (lane & 31) * 16;     // byte-in-row 0..496
        #pragma unroll
        for (int j = 0; j < 8; ++j) {
            int rl = rl_base + 2 * j + lr;
            const ushort* src = eb + (size_t)(e0 + rl) * PDIM + ((cb ^ ((rl & 7) << 4)) >> 1);
            dma16(src, &lds_e[(size_t)(rl_base + 2 * j) * PDIM]);
        }
    }

    // ---- stage pair/mask tile rows owned by this wave (linear) ----
    {
        int lr = lane >> 4;            // 0..3
        int lc = (lane & 15) * 4;      // float col
        #pragma unroll
        for (int j = 0; j < 4; ++j) {
            int r0 = wave * 16 + j * 4;
            size_t goff = (size_t)(u0 + r0 + lr) * EDIM + e0 + lc;
            dma16(pm + goff, &lds_pair[r0][0]);
            dma16(mm + goff, &lds_mask[r0][0]);
        }
    }

    // ---- af frags: 8x16B batched into regs, same FIFO, same drain ----
    const ushort* Au = u_p + (size_t)b * UDIM * PDIM + (size_t)(u0 + wave * 16 + m) * PDIM + quad * 8;
    bf16x8 af[8];
    #pragma unroll
    for (int i = 0; i < 8; ++i) af[i] = *(const bf16x8*)(Au + 32 * i);

    float bw = bpp_w_p[0], bb = bpp_b_p[0];

    asm volatile("s_waitcnt vmcnt(0)" ::: "memory");
    __syncthreads();

    // ---- MFMA loop, B frags from swizzled LDS ----
    int rowmask = (m & 7) << 4;
    f32x4 acc[4] = {};
    #pragma unroll
    for (int i = 0; i < 8; ++i) {
        #pragma unroll
        for (int nt = 0; nt < 4; ++nt) {
            int elem = (nt * 16 + m) * PDIM + (((quad * 16 + 64 * i) ^ rowmask) >> 1);
            bf16x8 bfr = *(const bf16x8*)(lds_e + elem);
            acc[nt] = __builtin_amdgcn_mfma_f32_16x16x32_bf16(af[i], bfr, acc[nt], 0, 0, 0);
        }
    }

    // ---- epilogue: gate + partial sums, all operands from LDS ----
    // C layout: row = quad*4+reg (tile-local + wave*16), col = nt*16 + m.
    float rsum[4] = {0.f, 0.f, 0.f, 0.f};
    float csum[4] = {0.f, 0.f, 0.f, 0.f};
    #pragma unroll
    for (int r = 0; r < 4; ++r) {
        int row = wave * 16 + quad * 4 + r;
        #pragma unroll
        for (int nt = 0; nt < 4; ++nt) {
            int col = nt * 16 + m;
            float mv = lds_mask[row][col];
            float pv = lds_pair[row][col];
            float arg = bw * pv + bb + mv * acc[nt][r];
            float s = mv / (1.f + __expf(-arg));
            rsum[r]  += s;
            csum[nt] += s;
        }
    }

    // Row sums: reduce across the 16 lanes of each quad (cols). Row is unique
    // to (wave, quad, r) -> direct atomicAdd from the quad leader.
    #pragma unroll
    for (int r = 0; r < 4; ++r) {
        float v = rsum[r];
        v += __shfl_xor(v, 1); v += __shfl_xor(v, 2);
        v += __shfl_xor(v, 4); v += __shfl_xor(v, 8);
        if (m == 0)
            atomicAdd(&row_sums[(size_t)b * UDIM + u0 + wave * 16 + quad * 4 + r], v);
    }

    // Col sums: reduce across quads (rows within strip), then across waves via LDS.
    #pragma unroll
    for (int nt = 0; nt < 4; ++nt) {
        float v = csum[nt];
        v += __shfl_xor(v, 16); v += __shfl_xor(v, 32);
        if (quad == 0) colred[wave][nt * 16 + m] = v;
    }
    __syncthreads();

    if (tid < 64) {
        float v = colred[0][tid] + colred[1][tid] + colred[2][tid] + colred[3][tid];
        atomicAdd(&col_sums[(size_t)b * EDIM + e0 + tid], v);
    }
}

// ---------------------------------------------------------------------------
// finish: out[b,0:256] = row_sums[b,:] @ u_enc[b]; out[b,256:512] = col_sums @ e_enc.
// (unchanged)
// ---------------------------------------------------------------------------
__global__ __launch_bounds__(256) void finish_kernel(
    const float* __restrict__ u_enc, const float* __restrict__ e_enc,
    const float* __restrict__ row_sums, const float* __restrict__ col_sums,
    float* __restrict__ out)
{
    int b = blockIdx.x;
    int half = blockIdx.y;
    int chunk = blockIdx.z;        // 0..63
    int d = threadIdx.x;

    const float* enc = half ? e_enc : u_enc;
    const float* s   = half ? col_sums : row_sums;

    int base = chunk * 16;
    float ev[16];
    #pragma unroll
    for (int j = 0; j < 16; ++j)
        ev[j] = enc[(size_t)(b * UDIM + base + j) * DDIM + d];

    float acc = 0.f;
    #pragma unroll
    for (int j = 0; j < 16; ++j)
        acc += s[(size_t)b * UDIM + base + j] * ev[j];

    atomicAdd(&out[(size_t)b * 2 * DDIM + half * DDIM + d], acc);
}

// ---------------------------------------------------------------------------
extern "C" void kernel_launch(void* const* d_in, const int* in_sizes, int n_in,
                              void* d_out, int out_size, void* d_ws, size_t ws_size,
                              hipStream_t stream)
{
    const float* u_enc    = (const float*)d_in[0];
    const float* e_enc    = (const float*)d_in[1];
    const float* pair_enc = (const float*)d_in[2];
    const float* ue_mask  = (const float*)d_in[3];
    const float* w_kernel = (const float*)d_in[4];
    const float* w_bias   = (const float*)d_in[5];
    const float* bpp_w    = (const float*)d_in[6];
    const float* bpp_b    = (const float*)d_in[7];
    float* out = (float*)d_out;

    // ws layout: u_p bf16 (4MB) | e_p bf16 (4MB) | wT bf16 (128KB) | sums fp32 (64KB)
    ushort* u_p = (ushort*)d_ws;
    ushort* e_p = u_p + (size_t)BDIM * UDIM * PDIM;
    ushort* wT  = e_p + (size_t)BDIM * EDIM * PDIM;
    float* row_sums = (float*)(wT + (size_t)DDIM * PDIM);
    float* col_sums = row_sums + BDIM * UDIM;

    prep_kernel<<<dim3(64), 256, 0, stream>>>(w_kernel, wT, row_sums, out, out_size);

    proj_kernel<<<dim3(1024), 256, 0, stream>>>(u_enc, e_enc, wT, w_bias, u_p, e_p);

    fused_kernel<<<dim3(2048), 256, 0, stream>>>(u_p, e_p, pair_enc, ue_mask,
                                                 bpp_w, bpp_b, row_sums, col_sums);

    finish_kernel<<<dim3(BDIM, 2, 64), 256, 0, stream>>>(u_enc, e_enc, row_sums, col_sums, out);
}

// Round 5
// 152.375 us; speedup vs baseline: 1.2029x; 1.0225x over previous
//
#include <hip/hip_runtime.h>

// Problem constants (SubOut_60206851555968): B=8, U=E=1024, D=P=256, fp32 in/out.
#define BDIM 8
#define UDIM 1024
#define EDIM 1024
#define DDIM 256
#define PDIM 256

typedef __attribute__((ext_vector_type(8))) short bf16x8;   // 8 bf16 = 4 VGPRs
typedef __attribute__((ext_vector_type(4))) float f32x4;    // clang ext_vector: legal in asm "v"

__device__ __forceinline__ short f2bf(float x) {
    unsigned u = __float_as_uint(x);
    unsigned r = (u + 0x7FFFu + ((u >> 16) & 1u)) >> 16;   // RNE
    return (short)r;
}

// Async global->LDS DMA, 16B per lane. LDS dest = wave-uniform base + lane*16;
// global src is per-lane (swizzled LDS layouts = pre-swizzle the SOURCE).
__device__ __forceinline__ void dma16(const void* g, void* lds) {
    __builtin_amdgcn_global_load_lds(
        (const __attribute__((address_space(1))) unsigned*)g,
        (__attribute__((address_space(3))) unsigned*)lds, 16, 0, 0);
}

// Keep-alive: forces x to be materialized in VGPRs at this program point.
// Round-1 lesson: hipcc sinks register-batched global loads to their uses
// (batch silently deleted, VGPR 48->40). An asm "use" is compiler-proof.
// ONLY apply to ext_vector / scalar types (HIP float4 is a class -> invalid
// asm operand; suspected cause of the round-4 container failure).
#define KEEP(x) asm volatile("" :: "v"(x))

// ---------------------------------------------------------------------------
// prep: wT[n][k] = bf16(w[k][n]); zero sums + out.  (unchanged)
// ---------------------------------------------------------------------------
__global__ __launch_bounds__(256) void prep_kernel(
    const float* __restrict__ w, ushort* __restrict__ wT,
    float* __restrict__ sums /* row_sums||col_sums, 16384 */,
    float* __restrict__ out, int out_size)
{
    int k  = threadIdx.x;          // D index
    int n0 = blockIdx.x * 4;       // P index base
    f32x4 wv = *(const f32x4*)(w + (size_t)k * PDIM + n0);
    wT[(size_t)(n0 + 0) * DDIM + k] = (ushort)f2bf(wv[0]);
    wT[(size_t)(n0 + 1) * DDIM + k] = (ushort)f2bf(wv[1]);
    wT[(size_t)(n0 + 2) * DDIM + k] = (ushort)f2bf(wv[2]);
    wT[(size_t)(n0 + 3) * DDIM + k] = (ushort)f2bf(wv[3]);
    int g = blockIdx.x * 256 + k;
    sums[g] = 0.f;                              // exactly 16384
    if (g < out_size) out[g] = 0.f;
}

// ---------------------------------------------------------------------------
// proj v4b: u_p/e_p = bf16(enc @ w + bias), MFMA 16x16x32 bf16.
// wT tile staged once/block into swizzled LDS (v3). The 16 batched A-vectors
// are KEEP-pinned before the drain so the compiler cannot sink them into the
// MFMA loop (round-1 failure mode). All global traffic (16 DMAs + 16 loads)
// is in flight simultaneously, drained once.
// ---------------------------------------------------------------------------
__global__ __launch_bounds__(256) void proj_kernel(
    const float* __restrict__ u_enc, const float* __restrict__ e_enc,
    const ushort* __restrict__ wT, const float* __restrict__ bias,
    ushort* __restrict__ u_p, ushort* __restrict__ e_p)
{
    __shared__ ushort lds_b[64 * 256];   // 32 KB, swizzled: byte = rl*512 + (cb ^ ((rl&7)<<4))

    int bid  = blockIdx.x;                 // 0..1023
    int lin  = (bid & 7) * 128 + (bid >> 3);
    int row0 = (lin >> 2) * 64;
    int col0 = (lin & 3) * 64;

    const float* A; ushort* C;
    if (row0 < BDIM * UDIM) { A = u_enc; C = u_p; }
    else                    { A = e_enc; C = e_p; row0 -= BDIM * UDIM; }

    int tid  = threadIdx.x;
    int wave = tid >> 6, lane = tid & 63;
    int m = lane & 15, quad = lane >> 4;

    // ---- stage wT rows [col0, col0+64) into LDS, swizzled source ----
    {
        int rl_base = wave * 16;
        int lr = lane >> 5;            // 0/1
        int cb = (lane & 31) * 16;     // 0..496
        #pragma unroll
        for (int j = 0; j < 8; ++j) {
            int rl = rl_base + 2 * j + lr;
            const ushort* src = wT + (size_t)(col0 + rl) * DDIM + ((cb ^ ((rl & 7) << 4)) >> 1);
            dma16(src, &lds_b[(size_t)(rl_base + 2 * j) * DDIM]);
        }
    }

    // ---- A strip: 16 x f32x4 batched into registers, KEEP-pinned ----
    const float* aptr = A + (size_t)(row0 + wave * 16 + m) * DDIM + quad * 8;
    f32x4 a[16];
    #pragma unroll
    for (int i = 0; i < 8; ++i) {
        a[2 * i]     = *(const f32x4*)(aptr + 32 * i);
        a[2 * i + 1] = *(const f32x4*)(aptr + 32 * i + 4);
    }
    #pragma unroll
    for (int i = 0; i < 16; ++i) KEEP(a[i]);

    asm volatile("s_waitcnt vmcnt(0)" ::: "memory");
    __syncthreads();

    int rowmask = (m & 7) << 4;        // swizzle term: B row = nt*16 + m -> row&7 = m&7
    f32x4 acc[4] = {};
    #pragma unroll
    for (int i = 0; i < 8; ++i) {
        bf16x8 af;
        af[0] = f2bf(a[2*i][0]);   af[1] = f2bf(a[2*i][1]);
        af[2] = f2bf(a[2*i][2]);   af[3] = f2bf(a[2*i][3]);
        af[4] = f2bf(a[2*i+1][0]); af[5] = f2bf(a[2*i+1][1]);
        af[6] = f2bf(a[2*i+1][2]); af[7] = f2bf(a[2*i+1][3]);
        #pragma unroll
        for (int nt = 0; nt < 4; ++nt) {
            int elem = (nt * 16 + m) * DDIM + (((quad * 16 + 64 * i) ^ rowmask) >> 1);
            bf16x8 bfr = *(const bf16x8*)(lds_b + elem);
            acc[nt] = __builtin_amdgcn_mfma_f32_16x16x32_bf16(af, bfr, acc[nt], 0, 0, 0);
        }
    }

    // C/D layout: col = lane&15, row = quad*4 + reg.
    #pragma unroll
    for (int nt = 0; nt < 4; ++nt) {
        int col = col0 + nt * 16 + m;
        float bv = bias[col];
        #pragma unroll
        for (int r = 0; r < 4; ++r) {
            int row = row0 + wave * 16 + quad * 4 + r;
            C[(size_t)row * PDIM + col] = (ushort)f2bf(acc[nt][r] + bv);
        }
    }
}

// ---------------------------------------------------------------------------
// fused v6b: op = u_p . e_p (MFMA), gate, row/col reduction.
// v5 structure (e-tile swizzled LDS, pair/mask LDS, one drain, 65KB ->
// 2 blocks/CU so stage of block n+2 overlaps compute of block n).
// af[8] KEEP-pinned before the drain — the last possibly-sunk global loads
// are provably batched in the same vmcnt FIFO as the DMAs.
// ---------------------------------------------------------------------------
__global__ __launch_bounds__(256) void fused_kernel(
    const ushort* __restrict__ u_p, const ushort* __restrict__ e_p,
    const float* __restrict__ pair_enc, const float* __restrict__ ue_mask,
    const float* __restrict__ bpp_w_p, const float* __restrict__ bpp_b_p,
    float* __restrict__ row_sums, float* __restrict__ col_sums)
{
    __shared__ ushort lds_e[64 * 256];   // 32 KB, swizzled (same scheme as proj)
    __shared__ float lds_pair[64][64];   // 16 KB, linear
    __shared__ float lds_mask[64][64];   // 16 KB, linear
    __shared__ float colred[4][64];      // 1 KB

    int bid  = blockIdx.x;          // 0..2047
    int b    = bid & 7;             // batch <-> XCD (FETCH 51->37MB win, kept)
    int tile = bid >> 3;            // 0..255
    int iu = tile >> 4, ie = tile & 15;
    int u0 = iu * 64, e0 = ie * 64;

    int tid  = threadIdx.x;
    int wave = tid >> 6, lane = tid & 63;
    int m = lane & 15, quad = lane >> 4;

    const float* pm = pair_enc + (size_t)b * UDIM * EDIM;
    const float* mm = ue_mask  + (size_t)b * UDIM * EDIM;
    const ushort* eb = e_p + (size_t)b * EDIM * PDIM;

    // ---- stage e-tile rows [e0, e0+64) into swizzled LDS ----
    {
        int rl_base = wave * 16;
        int lr = lane >> 5;            // 0/1
        int cb = (lane & 31) * 16;     // byte-in-row 0..496
        #pragma unroll
        for (int j = 0; j < 8; ++j) {
            int rl = rl_base + 2 * j + lr;
            const ushort* src = eb + (size_t)(e0 + rl) * PDIM + ((cb ^ ((rl & 7) << 4)) >> 1);
            dma16(src, &lds_e[(size_t)(rl_base + 2 * j) * PDIM]);
        }
    }

    // ---- stage pair/mask tile rows owned by this wave (linear) ----
    {
        int lr = lane >> 4;            // 0..3
        int lc = (lane & 15) * 4;      // float col
        #pragma unroll
        for (int j = 0; j < 4; ++j) {
            int r0 = wave * 16 + j * 4;
            size_t goff = (size_t)(u0 + r0 + lr) * EDIM + e0 + lc;
            dma16(pm + goff, &lds_pair[r0][0]);
            dma16(mm + goff, &lds_mask[r0][0]);
        }
    }

    // ---- af frags: 8x16B batched into regs, KEEP-pinned, same drain ----
    const ushort* Au = u_p + (size_t)b * UDIM * PDIM + (size_t)(u0 + wave * 16 + m) * PDIM + quad * 8;
    bf16x8 af[8];
    #pragma unroll
    for (int i = 0; i < 8; ++i) af[i] = *(const bf16x8*)(Au + 32 * i);
    #pragma unroll
    for (int i = 0; i < 8; ++i) KEEP(af[i]);

    float bw = bpp_w_p[0], bb = bpp_b_p[0];

    asm volatile("s_waitcnt vmcnt(0)" ::: "memory");
    __syncthreads();

    // ---- MFMA loop, B frags from swizzled LDS ----
    int rowmask = (m & 7) << 4;
    f32x4 acc[4] = {};
    #pragma unroll
    for (int i = 0; i < 8; ++i) {
        #pragma unroll
        for (int nt = 0; nt < 4; ++nt) {
            int elem = (nt * 16 + m) * PDIM + (((quad * 16 + 64 * i) ^ rowmask) >> 1);
            bf16x8 bfr = *(const bf16x8*)(lds_e + elem);
            acc[nt] = __builtin_amdgcn_mfma_f32_16x16x32_bf16(af[i], bfr, acc[nt], 0, 0, 0);
        }
    }

    // ---- epilogue: gate + partial sums, all operands from LDS ----
    float rsum[4] = {0.f, 0.f, 0.f, 0.f};
    float csum[4] = {0.f, 0.f, 0.f, 0.f};
    #pragma unroll
    for (int r = 0; r < 4; ++r) {
        int row = wave * 16 + quad * 4 + r;
        #pragma unroll
        for (int nt = 0; nt < 4; ++nt) {
            int col = nt * 16 + m;
            float mv = lds_mask[row][col];
            float pv = lds_pair[row][col];
            float arg = bw * pv + bb + mv * acc[nt][r];
            float s = mv / (1.f + __expf(-arg));
            rsum[r]  += s;
            csum[nt] += s;
        }
    }

    // Row sums: reduce across the 16 lanes of each quad (cols).
    #pragma unroll
    for (int r = 0; r < 4; ++r) {
        float v = rsum[r];
        v += __shfl_xor(v, 1); v += __shfl_xor(v, 2);
        v += __shfl_xor(v, 4); v += __shfl_xor(v, 8);
        if (m == 0)
            atomicAdd(&row_sums[(size_t)b * UDIM + u0 + wave * 16 + quad * 4 + r], v);
    }

    // Col sums: reduce across quads, then across waves via LDS.
    #pragma unroll
    for (int nt = 0; nt < 4; ++nt) {
        float v = csum[nt];
        v += __shfl_xor(v, 16); v += __shfl_xor(v, 32);
        if (quad == 0) colred[wave][nt * 16 + m] = v;
    }
    __syncthreads();

    if (tid < 64) {
        float v = colred[0][tid] + colred[1][tid] + colred[2][tid] + colred[3][tid];
        atomicAdd(&col_sums[(size_t)b * EDIM + e0 + tid], v);
    }
}

// ---------------------------------------------------------------------------
// finish v3b: out[b,0:256] = row_sums[b,:] @ u_enc[b]; out[b,256:512] = col_sums @ e_enc.
// 32-row chunks (was 16): MLP 32, 512 blocks (2/CU), half the atomic rounds.
// ev[32] (scalar floats) KEEP-pinned so the batch survives.
// ---------------------------------------------------------------------------
__global__ __launch_bounds__(256) void finish_kernel(
    const float* __restrict__ u_enc, const float* __restrict__ e_enc,
    const float* __restrict__ row_sums, const float* __restrict__ col_sums,
    float* __restrict__ out)
{
    int b = blockIdx.x;
    int half = blockIdx.y;
    int chunk = blockIdx.z;        // 0..31
    int d = threadIdx.x;

    const float* enc = half ? e_enc : u_enc;
    const float* s   = half ? col_sums : row_sums;

    int base = chunk * 32;
    float ev[32];
    #pragma unroll
    for (int j = 0; j < 32; ++j)
        ev[j] = enc[(size_t)(b * UDIM + base + j) * DDIM + d];
    #pragma unroll
    for (int j = 0; j < 32; ++j) KEEP(ev[j]);

    float acc = 0.f;
    #pragma unroll
    for (int j = 0; j < 32; ++j)
        acc += s[(size_t)b * UDIM + base + j] * ev[j];

    atomicAdd(&out[(size_t)b * 2 * DDIM + half * DDIM + d], acc);
}

// ---------------------------------------------------------------------------
extern "C" void kernel_launch(void* const* d_in, const int* in_sizes, int n_in,
                              void* d_out, int out_size, void* d_ws, size_t ws_size,
                              hipStream_t stream)
{
    const float* u_enc    = (const float*)d_in[0];
    const float* e_enc    = (const float*)d_in[1];
    const float* pair_enc = (const float*)d_in[2];
    const float* ue_mask  = (const float*)d_in[3];
    const float* w_kernel = (const float*)d_in[4];
    const float* w_bias   = (const float*)d_in[5];
    const float* bpp_w    = (const float*)d_in[6];
    const float* bpp_b    = (const float*)d_in[7];
    float* out = (float*)d_out;

    // ws layout: u_p bf16 (4MB) | e_p bf16 (4MB) | wT bf16 (128KB) | sums fp32 (64KB)
    ushort* u_p = (ushort*)d_ws;
    ushort* e_p = u_p + (size_t)BDIM * UDIM * PDIM;
    ushort* wT  = e_p + (size_t)BDIM * EDIM * PDIM;
    float* row_sums = (float*)(wT + (size_t)DDIM * PDIM);
    float* col_sums = row_sums + BDIM * UDIM;

    prep_kernel<<<dim3(64), 256, 0, stream>>>(w_kernel, wT, row_sums, out, out_size);

    proj_kernel<<<dim3(1024), 256, 0, stream>>>(u_enc, e_enc, wT, w_bias, u_p, e_p);

    fused_kernel<<<dim3(2048), 256, 0, stream>>>(u_p, e_p, pair_enc, ue_mask,
                                                 bpp_w, bpp_b, row_sums, col_sums);

    finish_kernel<<<dim3(BDIM, 2, 32), 256, 0, stream>>>(u_enc, e_enc, row_sums, col_sums, out);
}